// Round 5
// baseline (910.101 us; speedup 1.0000x reference)
//
#include <hip/hip_runtime.h>
#include <math.h>

// ============================================================================
// FeatureAlign (2-level DCNv2 pyramid + SEM head).
// R4: GN y round-trip eliminated (gn_partials + gn_apply_fused recompute).
// R5: dcn_col gather vectorized via channel-quad x layout [c/4][HW][4].
// R6: mconv barrier-free/LDS-free (offset GEMM stores transposed fp16).
// R7 (REVERTED): barrier-free DCN GEMM lost to scattered B loads (120us).
// R8: DCN GEMM back to LDS structure + two parameter fixes:
//     (a) 128Mx32N tile (mgemm32) -> grid 1024 = 4 blocks/CU (was 2);
//     (b) LDS stride 40 -> 42 halves (21 coprime 32) kills the 8-way
//         staging bank conflicts (1.4e7 cycles) in all LDS GEMMs.
//     MFMA accumulation order unchanged (bitwise-identical outputs).
// ============================================================================

typedef _Float16 h_t;
typedef _Float16 h2 __attribute__((ext_vector_type(2)));
typedef _Float16 h4 __attribute__((ext_vector_type(4)));
typedef _Float16 h8 __attribute__((ext_vector_type(8)));
typedef float f4 __attribute__((ext_vector_type(4)));

static inline int cdiv(long long a, long long b) { return (int)((a + b - 1) / b); }

#define LDST 42  // LDS row stride in halves (84B; 21 coprime 32 -> conflict-free)

// ---------------- weight prep: fp32 [M][K] -> swizzled fp16 hi/lo ----------------
// layout: idx = ((mblk*(K/32)+c)*2 + s)*4096 + m*32 + k   (mblk: 128-row block)
// PERM=1: k-space permuted tap-major: k' = tap*256 + ch, source k = ch*9 + tap.
template <int PERM>
__global__ void prep_w_kernel(const float* __restrict__ W, h_t* __restrict__ Wp,
                              int M, int K) {
  long long idx = (long long)blockIdx.x * 256 + threadIdx.x;
  if (idx >= 512LL * K) return;
  int within = (int)(idx & 4095);
  int m = within >> 5, k = within & 31;
  long long t2 = idx >> 12;
  int s = (int)(t2 & 1);
  long long t3 = t2 >> 1;
  int nck = K >> 5;
  int c = (int)(t3 % nck), mblk = (int)(t3 / nck);
  int gm = mblk * 128 + m, gk = c * 32 + k;
  if (PERM) gk = (gk & 255) * 9 + (gk >> 8);
  float f = (gm < M) ? W[(long long)gm * K + gk] : 0.f;
  h_t hi = (h_t)f;
  Wp[idx] = s ? (h_t)(f - (float)hi) : hi;
}

// ---------------- bilinear 2x upsample -> channel-quad layout ----------------
template <int LOGOW>
__global__ void upsample2x_q_kernel(const float* __restrict__ in, float* __restrict__ out,
                                    int NQ) {
  const int OW = 1 << LOGOW, OHW = OW * OW, IW = OW >> 1;
  long long idx = (long long)blockIdx.x * 256 + threadIdx.x;
  if (idx >= (long long)NQ * OHW) return;
  int p = (int)(idx & (OHW - 1));
  int q = (int)(idx >> (2 * LOGOW));
  int oh = p >> LOGOW, ow = p & (OW - 1);
  int iy = oh >> 1, ix = ow >> 1;
  int iy2 = (oh & 1) ? min(iy + 1, IW - 1) : max(iy - 1, 0);
  int ix2 = (ow & 1) ? min(ix + 1, IW - 1) : max(ix - 1, 0);
  const float* pb = in + (long long)q * 4 * IW * IW;
  f4 o;
#pragma unroll
  for (int j = 0; j < 4; ++j) {
    const float* pc = pb + (long long)j * IW * IW;
    o[j] = 0.5625f * pc[iy * IW + ix] + 0.1875f * (pc[iy * IW + ix2] + pc[iy2 * IW + ix])
         + 0.0625f * pc[iy2 * IW + ix2];
  }
  *(f4*)(out + idx * 4) = o;
}

// ---------------- channel concat -> fp16: out[b] = [A[b], scale*B[b]] ----------------
template <typename TA>
__global__ void concat_h_kernel(const TA* __restrict__ A, const float* __restrict__ Bp,
                                h_t* __restrict__ out, int C1, int C2, int HW, float scale) {
  long long idx = (long long)blockIdx.x * blockDim.x + threadIdx.x;
  long long total = 4LL * (C1 + C2) * HW;
  if (idx >= total) return;
  int p = (int)(idx % HW);
  long long t = idx / HW;
  int c = (int)(t % (C1 + C2));
  int b = (int)(t / (C1 + C2));
  float v;
  if (c < C1) v = (float)A[((long long)b * C1 + c) * HW + p];
  else        v = scale * Bp[((long long)b * C2 + (c - C1)) * HW + p];
  out[idx] = (h_t)v;
}

// ---------------- concat A-half only: out[b][0..C1) = A ----------------
template <typename TA>
__global__ void concat_a_kernel(const TA* __restrict__ A, h_t* __restrict__ out,
                                int C1, int Ctot, int HW) {
  long long idx = (long long)blockIdx.x * 256 + threadIdx.x;
  long long total = 4LL * C1 * HW;
  if (idx >= total) return;
  int p = (int)(idx % HW);
  long long t = idx / HW;
  int c = (int)(t % C1);
  int b = (int)(t / C1);
  out[((long long)b * Ctot + c) * HW + p] = (h_t)(float)A[((long long)b * C1 + c) * HW + p];
}

// ---------------- concat B-half from quad layout: out[b][C1+c] = scale*Bq ----------------
__global__ void concat_bq_kernel(const float* __restrict__ xq, h_t* __restrict__ out,
                                 int C1, int C2, int HW, float scale) {
  long long idx = (long long)blockIdx.x * 256 + threadIdx.x; // 4 * (C2/4) * HW
  long long total = 4LL * (C2 >> 2) * HW;
  if (idx >= total) return;
  int p = (int)(idx % HW);
  long long t = idx / HW;
  int q = (int)(t % (C2 >> 2));
  int b = (int)(t / (C2 >> 2));
  f4 v = *(const f4*)(xq + ((long long)(b * (C2 >> 2) + q) * HW + p) * 4);
  h_t* ob = out + ((long long)b * (C1 + C2) + C1 + q * 4) * HW + p;
  ob[0]            = (h_t)(scale * v.x);
  ob[(long long)HW]     = (h_t)(scale * v.y);
  ob[(long long)2 * HW] = (h_t)(scale * v.z);
  ob[(long long)3 * HW] = (h_t)(scale * v.w);
}

// ---------------- MFMA GEMM (LDS-staged, 128Mx64N): C[z] = W @ B[z] ----------------
// OUTH: 0 = f32 [M][N]; 1 = fp16 [M][N]; 2 = fp16 TRANSPOSED [N][256] (h4 st).
template <int RELU, int OUTH, int TWO>
__global__ __launch_bounds__(256) void mgemm_kernel(
    const h_t* __restrict__ Wp, const h_t* __restrict__ B, void* __restrict__ Cv,
    const float* __restrict__ bias, int Mstore, int N, int K,
    long long sB, long long sC) {
  __shared__ __align__(16) h_t Ah[128 * LDST];
  __shared__ __align__(16) h_t Al[TWO ? 128 * LDST : 8];
  __shared__ __align__(16) h_t Bs[64 * LDST];
  const int tid = threadIdx.x;
  const int bn = blockIdx.x * 64;
  const int mblk = blockIdx.y;
  const int z = blockIdx.z;
  const h_t* Bb = B + (long long)z * sB;
  const int nck = K >> 5;
  const h_t* Wt = Wp + (long long)mblk * nck * 8192 +
                  (TWO ? (tid << 5) : ((tid >> 1) << 5) + ((tid & 1) << 4));
  const int wid = tid >> 6, lane = tid & 63;
  const int wm = (wid >> 1) * 64, wn = (wid & 1) * 32;
  const int l15 = lane & 15, q = lane >> 4;
  f4 acc[4][2] = {};
  h_t* Adst = TWO ? (tid >= 128 ? Al : Ah) + (tid & 127) * LDST
                  : Ah + (tid >> 1) * LDST + ((tid & 1) << 4);
  const int kp = tid >> 4, ngf = tid & 15;
  h_t* Bdst = Bs + ngf * 4 * LDST + kp * 2;
  for (int c = 0; c < nck; ++c) {
    const h_t* asrc = Wt + c * 8192;
    if (TWO) {
#pragma unroll
      for (int i = 0; i < 4; ++i)
        *(h8*)(Adst + i * 8) = *(const h8*)(asrc + i * 8);
    } else {
      *(h8*)(Adst) = *(const h8*)(asrc);
      *(h8*)(Adst + 8) = *(const h8*)(asrc + 8);
    }
    const h_t* bsrc = Bb + (long long)(c * 32 + kp * 2) * N + bn + ngf * 4;
    h4 r0 = *(const h4*)bsrc;
    h4 r1 = *(const h4*)(bsrc + N);
#pragma unroll
    for (int j = 0; j < 4; ++j) {
      h2 v; v.x = r0[j]; v.y = r1[j];
      *(h2*)(Bdst + j * LDST) = v;
    }
    __syncthreads();
    h8 bf[2];
#pragma unroll
    for (int nt = 0; nt < 2; ++nt)
      bf[nt] = *(const h8*)(Bs + (wn + nt * 16 + l15) * LDST + q * 8);
#pragma unroll
    for (int mt = 0; mt < 4; ++mt) {
      const int ro = (wm + mt * 16 + l15) * LDST + q * 8;
      h8 ahi = *(const h8*)(Ah + ro);
#pragma unroll
      for (int nt = 0; nt < 2; ++nt)
        acc[mt][nt] = __builtin_amdgcn_mfma_f32_16x16x32_f16(ahi, bf[nt], acc[mt][nt], 0, 0, 0);
      if (TWO) {
        h8 alo = *(const h8*)(Al + ro);
#pragma unroll
        for (int nt = 0; nt < 2; ++nt)
          acc[mt][nt] = __builtin_amdgcn_mfma_f32_16x16x32_f16(alo, bf[nt], acc[mt][nt], 0, 0, 0);
      }
    }
    __syncthreads();
  }
#pragma unroll
  for (int mt = 0; mt < 4; ++mt)
#pragma unroll
    for (int nt = 0; nt < 2; ++nt) {
      int n = bn + wn + nt * 16 + l15;
      if (OUTH == 2) {
        int row0 = mblk * 128 + wm + mt * 16 + q * 4;
        if (row0 + 3 < Mstore) {
          h4 hv;
#pragma unroll
          for (int r = 0; r < 4; ++r) {
            float v = acc[mt][nt][r] + (bias ? bias[row0 + r] : 0.f);
            if (RELU) v = fmaxf(v, 0.f);
            hv[r] = (h_t)v;
          }
          *(h4*)((h_t*)Cv + (long long)z * sC + (long long)n * 256 + row0) = hv;
        }
      } else {
#pragma unroll
        for (int r = 0; r < 4; ++r) {
          int row = mblk * 128 + wm + mt * 16 + q * 4 + r;
          if (row < Mstore) {
            float v = acc[mt][nt][r] + (bias ? bias[row] : 0.f);
            if (RELU) v = fmaxf(v, 0.f);
            if (OUTH) ((h_t*)Cv)[(long long)z * sC + (long long)row * N + n] = (h_t)v;
            else      ((float*)Cv)[(long long)z * sC + (long long)row * N + n] = v;
          }
        }
      }
    }
}

// ---------------- DCN GEMM (LDS-staged, 128Mx32N, TWO-term, RELU) ----------------
// Same structure as mgemm TWO but 32-wide N tile: grid doubles -> 4 blocks/CU.
// Waves: wid 0..3 each own 32Mx32N (mt 2 x nt 2). Bitwise-identical acc order.
template <int OUTH>
__global__ __launch_bounds__(256) void mgemm32_kernel(
    const h_t* __restrict__ Wp, const h_t* __restrict__ B, void* __restrict__ Cv,
    const float* __restrict__ bias, int N, int K, long long sB, long long sC) {
  __shared__ __align__(16) h_t Ah[128 * LDST];
  __shared__ __align__(16) h_t Al[128 * LDST];
  __shared__ __align__(16) h_t Bs[32 * LDST];
  const int tid = threadIdx.x;
  const int bn = blockIdx.x * 32;
  const int mblk = blockIdx.y;
  const int z = blockIdx.z;
  const h_t* Bb = B + (long long)z * sB;
  const int nck = K >> 5;
  const h_t* Wt = Wp + (long long)mblk * nck * 8192 + (tid << 5);
  const int wid = tid >> 6, lane = tid & 63;
  const int l15 = lane & 15, q = lane >> 4;
  f4 acc[2][2] = {};
  h_t* Adst = (tid >= 128 ? Al : Ah) + (tid & 127) * LDST;
  const int kp = tid >> 3, ngf = tid & 7;   // 32 k-rows x 8 pixel-groups
  h_t* Bdst = Bs + ngf * 4 * LDST + kp;
  for (int c = 0; c < nck; ++c) {
    const h_t* asrc = Wt + c * 8192;
#pragma unroll
    for (int i = 0; i < 4; ++i)
      *(h8*)(Adst + i * 8) = *(const h8*)(asrc + i * 8);
    const h_t* bsrc = Bb + (long long)(c * 32 + kp) * N + bn + ngf * 4;
    h4 r0 = *(const h4*)bsrc;
#pragma unroll
    for (int j = 0; j < 4; ++j) Bdst[j * LDST] = r0[j];
    __syncthreads();
    h8 bf[2];
#pragma unroll
    for (int nt = 0; nt < 2; ++nt)
      bf[nt] = *(const h8*)(Bs + (nt * 16 + l15) * LDST + q * 8);
#pragma unroll
    for (int mt = 0; mt < 2; ++mt) {
      const int ro = (wid * 32 + mt * 16 + l15) * LDST + q * 8;
      h8 ahi = *(const h8*)(Ah + ro);
#pragma unroll
      for (int nt = 0; nt < 2; ++nt)
        acc[mt][nt] = __builtin_amdgcn_mfma_f32_16x16x32_f16(ahi, bf[nt], acc[mt][nt], 0, 0, 0);
      h8 alo = *(const h8*)(Al + ro);
#pragma unroll
      for (int nt = 0; nt < 2; ++nt)
        acc[mt][nt] = __builtin_amdgcn_mfma_f32_16x16x32_f16(alo, bf[nt], acc[mt][nt], 0, 0, 0);
    }
    __syncthreads();
  }
#pragma unroll
  for (int mt = 0; mt < 2; ++mt)
#pragma unroll
    for (int nt = 0; nt < 2; ++nt) {
      int n = bn + nt * 16 + l15;
#pragma unroll
      for (int r = 0; r < 4; ++r) {
        int row = mblk * 128 + wid * 32 + mt * 16 + q * 4 + r;
        float v = fmaxf(acc[mt][nt][r] + bias[row], 0.f);
        if (OUTH) ((h_t*)Cv)[(long long)z * sC + (long long)row * N + n] = (h_t)v;
        else      ((float*)Cv)[(long long)z * sC + (long long)row * N + n] = v;
      }
    }
}

// ---------------- conv3x3 as MFMA implicit GEMM, barrier-free ----------------
template <int LOGW>
__global__ __launch_bounds__(256) void mconv_kernel(
    const h_t* __restrict__ Wp, const h_t* __restrict__ OffT, float* __restrict__ Cf,
    const float* __restrict__ bias, int HW) {
  const int W = 1 << LOGW, H = HW >> LOGW;
  const int tid = threadIdx.x;
  const int p0 = blockIdx.x * 64;
  const int mblk = blockIdx.y;
  const int z = blockIdx.z;
  const h_t* Ot = OffT + (long long)z * HW * 256;
  const h_t* Wb = Wp + (long long)mblk * 72 * 8192;
  const int wid = tid >> 6, lane = tid & 63;
  const int wm = (wid >> 1) * 64, wn = (wid & 1) * 32;
  const int l15 = lane & 15, q = lane >> 4;
  const int aoff = (wm + l15) * 32 + q * 8;
  f4 acc[4][2] = {};
  int py[2], px[2];
#pragma unroll
  for (int nt = 0; nt < 2; ++nt) {
    int p = p0 + wn + nt * 16 + l15;
    py[nt] = p >> LOGW;
    px[nt] = p & (W - 1);
  }
  for (int tap = 0; tap < 9; ++tap) {
    const int dy = tap / 3 - 1, dx = tap - (tap / 3) * 3 - 1;
    const h_t* bsrc[2];
    bool bok[2];
#pragma unroll
    for (int nt = 0; nt < 2; ++nt) {
      int sy = py[nt] + dy, sx = px[nt] + dx;
      bok[nt] = (sy >= 0) & (sy < H) & (sx >= 0) & (sx < W);
      int sp = bok[nt] ? (sy * W + sx) : 0;
      bsrc[nt] = Ot + (long long)sp * 256 + q * 8;
    }
#pragma unroll 2
    for (int c2 = 0; c2 < 8; ++c2) {
      const int c = tap * 8 + c2;
      h8 bf[2];
#pragma unroll
      for (int nt = 0; nt < 2; ++nt) {
        h8 v = {};
        if (bok[nt]) v = *(const h8*)(bsrc[nt] + c2 * 32);
        bf[nt] = v;
      }
      const h_t* aw = Wb + (long long)c * 8192 + aoff;
#pragma unroll
      for (int mt = 0; mt < 4; ++mt) {
        h8 af = *(const h8*)(aw + mt * 512);
#pragma unroll
        for (int nt = 0; nt < 2; ++nt)
          acc[mt][nt] = __builtin_amdgcn_mfma_f32_16x16x32_f16(af, bf[nt], acc[mt][nt], 0, 0, 0);
      }
    }
  }
  float* Cb = Cf + (long long)z * 216 * HW;
#pragma unroll
  for (int mt = 0; mt < 4; ++mt)
#pragma unroll
    for (int nt = 0; nt < 2; ++nt) {
      int n = p0 + wn + nt * 16 + l15;
#pragma unroll
      for (int r = 0; r < 4; ++r) {
        int row = mblk * 128 + wm + mt * 16 + q * 4 + r;
        if (row < 216)
          Cb[(long long)row * HW + n] = acc[mt][nt][r] + bias[row];
      }
    }
}

// ---------------- DCNv2 column build (fp16 out): col[bz][(g*32+c)*9+k][p] ----------------
// x in channel-quad layout [c/4][HW][4]: one dwordx4 per corner per 4 channels.
template <int LOGW>
__global__ __launch_bounds__(256) void dcn_col_kernel(
    const float* __restrict__ x, const float* __restrict__ om,
    h_t* __restrict__ col, int b0) {
  const int W = 1 << LOGW, H = W, HW = W * W;
  int p = blockIdx.x * 256 + threadIdx.x;
  int gk = blockIdx.y;           // 0..71
  int g = gk / 9, k9 = gk - g * 9;
  int bz = blockIdx.z;
  int b = b0 + bz;
  int h = p >> LOGW, wc = p & (W - 1);
  const float* omb = om + (long long)b * 216 * HW;
  float offy = omb[(long long)gk * HW + p];
  float offx = omb[(long long)(72 + gk) * HW + p];
  float mraw = omb[(long long)(144 + gk) * HW + p];
  float mask = 1.f / (1.f + expf(-mraw));
  float y = (float)h + (float)(k9 / 3 - 1) + offy;
  float xx = (float)wc + (float)(k9 % 3 - 1) + offx;
  float y0f = floorf(y), x0f = floorf(xx);
  int y0 = (int)y0f, x0 = (int)x0f;
  float fy = y - y0f, fx = xx - x0f;
  float w00 = (1.f - fy) * (1.f - fx), w01 = (1.f - fy) * fx;
  float w10 = fy * (1.f - fx), w11 = fy * fx;
  bool iy0 = (y0 >= 0) & (y0 < H), iy1 = (y0 + 1 >= 0) & (y0 + 1 < H);
  bool ix0 = (x0 >= 0) & (x0 < W), ix1 = (x0 + 1 >= 0) & (x0 + 1 < W);
  w00 = (iy0 & ix0) ? w00 : 0.f;
  w01 = (iy0 & ix1) ? w01 : 0.f;
  w10 = (iy1 & ix0) ? w10 : 0.f;
  w11 = (iy1 & ix1) ? w11 : 0.f;
  int y0c = min(max(y0, 0), H - 1), y1c = min(max(y0 + 1, 0), H - 1);
  int x0c = min(max(x0, 0), W - 1), x1c = min(max(x0 + 1, 0), W - 1);
  int i00 = y0c * W + x0c, i01 = y0c * W + x1c, i10 = y1c * W + x0c, i11 = y1c * W + x1c;
  const float* xb = x + ((long long)b * 256 + g * 32) * HW;
  h_t* cb = col + ((long long)bz * 2304 + (long long)(g * 32) * 9 + k9) * HW + p;
#pragma unroll 1
  for (int qd = 0; qd < 8; qd += 2) {
    f4 a00[2], a01[2], a10[2], a11[2];
#pragma unroll
    for (int u = 0; u < 2; ++u) {
      const float* xq = xb + (long long)(qd + u) * HW * 4;
      a00[u] = *(const f4*)(xq + i00 * 4);
      a01[u] = *(const f4*)(xq + i01 * 4);
      a10[u] = *(const f4*)(xq + i10 * 4);
      a11[u] = *(const f4*)(xq + i11 * 4);
    }
#pragma unroll
    for (int u = 0; u < 2; ++u)
#pragma unroll
      for (int j = 0; j < 4; ++j) {
        float v = w00 * a00[u][j] + w01 * a01[u][j] + w10 * a10[u][j] + w11 * a11[u][j];
        cb[(long long)((qd + u) * 4 + j) * 9 * HW] = (h_t)(v * mask);
      }
  }
}

// ---------------- channel avg/max of up2x(f3c fp16) at 128x128 ----------------
__global__ void avgmax_kernel(const h_t* __restrict__ f3c, float* __restrict__ am) {
  int tid = threadIdx.x;
  int P = blockIdx.x * 64 + (tid >> 2);   // global pixel 0..65535
  int cq = tid & 3;
  int b = P >> 14, p = P & 16383;
  int oh = p >> 7, ow = p & 127;
  int iy = oh >> 1, ix = ow >> 1;
  int iy2 = (oh & 1) ? min(iy + 1, 63) : max(iy - 1, 0);
  int ix2 = (ow & 1) ? min(ix + 1, 63) : max(ix - 1, 0);
  int i00 = iy * 64 + ix, i01 = iy * 64 + ix2, i10 = iy2 * 64 + ix, i11 = iy2 * 64 + ix2;
  const h_t* base = f3c + (long long)b * 512 * 4096 + (long long)cq * 4096;
  float sum = 0.f, mx = -3.4e38f;
  for (int c = 0; c < 128; c++) {
    const h_t* pc = base + (long long)c * 4 * 4096;
    float v = 0.5625f * (float)pc[i00] + 0.1875f * ((float)pc[i01] + (float)pc[i10])
            + 0.0625f * (float)pc[i11];
    sum += v;
    mx = fmaxf(mx, v);
  }
  sum += __shfl_xor(sum, 1); sum += __shfl_xor(sum, 2);
  mx = fmaxf(mx, __shfl_xor(mx, 1)); mx = fmaxf(mx, __shfl_xor(mx, 2));
  if (cq == 0) {
    am[(long long)b * 2 * 16384 + p] = sum * (1.f / 512.f);
    am[(long long)b * 2 * 16384 + 16384 + p] = mx;
  }
}

// ---------------- conv7x7 (2->1) + BN + sigmoid -> sa ----------------
__global__ void sa_kernel(const float* __restrict__ am, const float* __restrict__ w_sa,
                          const float* __restrict__ bn_g, const float* __restrict__ bn_b,
                          const float* __restrict__ bn_m, const float* __restrict__ bn_v,
                          float* __restrict__ sa) {
  int idx = blockIdx.x * 64 + threadIdx.x; // 4*16384, 64-thread blocks
  int b = idx >> 14, p = idx & 16383;
  int oh = p >> 7, ow = p & 127;
  float acc = 0.f;
  for (int ci = 0; ci < 2; ci++) {
    const float* base = am + ((long long)b * 2 + ci) * 16384;
    for (int dy = 0; dy < 7; dy++) {
      int yy = oh + dy - 3;
      if (yy < 0 || yy > 127) continue;
      for (int dx = 0; dx < 7; dx++) {
        int xx = ow + dx - 3;
        if (xx < 0 || xx > 127) continue;
        acc += w_sa[ci * 49 + dy * 7 + dx] * base[yy * 128 + xx];
      }
    }
  }
  float a = (acc - bn_m[0]) * rsqrtf(bn_v[0] + 1e-5f);
  a = a * bn_g[0] + bn_b[0];
  sa[idx] = 1.f / (1.f + expf(-a));
}

// ---------------- GN stage-1: y = (1+sa)*up2x(z), partial sums only ----------------
__global__ __launch_bounds__(256) void gn_partials_kernel(
    const float* __restrict__ z, const float* __restrict__ sa,
    float2* __restrict__ partials) {
  long long idx = (long long)blockIdx.x * 256 + threadIdx.x; // 16,777,216
  int ow = (int)(idx & 127);
  long long t = idx >> 7;
  int oh = (int)(t & 127);
  t >>= 7;
  int c = (int)(t & 255);
  int b = (int)(t >> 8);
  int iy = oh >> 1, ix = ow >> 1;
  int iy2 = (oh & 1) ? min(iy + 1, 63) : max(iy - 1, 0);
  int ix2 = (ow & 1) ? min(ix + 1, 63) : max(ix - 1, 0);
  const float* zp = z + (long long)(b * 256 + c) * 4096;
  float v = 0.5625f * zp[iy * 64 + ix] + 0.1875f * (zp[iy * 64 + ix2] + zp[iy2 * 64 + ix])
          + 0.0625f * zp[iy2 * 64 + ix2];
  float s = sa[((long long)b << 14) + (oh << 7) + ow];
  float y = v * (1.f + s);
  float ps = y, pss = y * y;
#pragma unroll
  for (int off = 32; off > 0; off >>= 1) {
    ps += __shfl_down(ps, off);
    pss += __shfl_down(pss, off);
  }
  __shared__ float rs[2][4];
  int lane = threadIdx.x & 63, wv = threadIdx.x >> 6;
  if (lane == 0) { rs[0][wv] = ps; rs[1][wv] = pss; }
  __syncthreads();
  if (threadIdx.x == 0) {
    float2 pr;
    pr.x = rs[0][0] + rs[0][1] + rs[0][2] + rs[0][3];
    pr.y = rs[1][0] + rs[1][1] + rs[1][2] + rs[1][3];
    partials[blockIdx.x] = pr;
  }
}

// ---------------- GN stage-2: reduce 512 partials per (b,g) -> mu, rstd ----------------
__global__ __launch_bounds__(256) void gn_reduce_kernel(const float2* __restrict__ partials,
                                                        float* __restrict__ stats) {
  int bg = blockIdx.x; // 0..127
  int b = bg >> 5, g = bg & 31;
  int base = b * 16384 + g * 512;
  float2 p0 = partials[base + threadIdx.x];
  float2 p1 = partials[base + 256 + threadIdx.x];
  float s = p0.x + p1.x, ss = p0.y + p1.y;
#pragma unroll
  for (int off = 32; off > 0; off >>= 1) {
    s += __shfl_down(s, off);
    ss += __shfl_down(ss, off);
  }
  __shared__ float rs[2][4];
  int lane = threadIdx.x & 63, wv = threadIdx.x >> 6;
  if (lane == 0) { rs[0][wv] = s; rs[1][wv] = ss; }
  __syncthreads();
  if (threadIdx.x == 0) {
    float S = rs[0][0] + rs[0][1] + rs[0][2] + rs[0][3];
    float SS = rs[1][0] + rs[1][1] + rs[1][2] + rs[1][3];
    float n = 8.f * 16384.f;
    float mu = S / n;
    float var = SS / n - mu * mu;
    stats[bg * 2] = mu;
    stats[bg * 2 + 1] = rsqrtf(var + 1e-5f);
  }
}

// ---------------- GN stage-3: recompute y, normalize, store ----------------
__global__ __launch_bounds__(256) void gn_apply_fused_kernel(
    const float* __restrict__ z, const float* __restrict__ sa,
    const float* __restrict__ stats, const float* __restrict__ gg,
    const float* __restrict__ gb, float* __restrict__ out) {
  long long i4 = (long long)blockIdx.x * 256 + threadIdx.x; // 4,194,304 float4s
  long long e = i4 << 2;
  int ow0 = (int)(e & 127);
  int oh = (int)((e >> 7) & 127);
  int c = (int)((e >> 14) & 255);
  int b = (int)(e >> 22);
  int bg = b * 32 + (c >> 3);
  float mu = stats[bg * 2], rstd = stats[bg * 2 + 1];
  float sc = rstd * gg[c];
  float sh = gb[c] - mu * sc;
  int iy = oh >> 1;
  int iy2 = (oh & 1) ? min(iy + 1, 63) : max(iy - 1, 0);
  const float* zp = z + (long long)(b * 256 + c) * 4096;
  f4 sv = *(const f4*)(sa + (((long long)b << 14) + (oh << 7) + ow0));
  f4 o;
#pragma unroll
  for (int j = 0; j < 4; ++j) {
    int ow = ow0 + j;
    int ix = ow >> 1;
    int ix2 = (ow & 1) ? min(ix + 1, 63) : max(ix - 1, 0);
    float v = 0.5625f * zp[iy * 64 + ix] + 0.1875f * (zp[iy * 64 + ix2] + zp[iy2 * 64 + ix])
            + 0.0625f * zp[iy2 * 64 + ix2];
    float y = v * (1.f + sv[j]);
    o[j] = y * sc + sh;
  }
  *(f4*)(out + e) = o;
}

// ============================================================================

extern "C" void kernel_launch(void* const* d_in, const int* in_sizes, int n_in,
                              void* d_out, int out_size, void* d_ws, size_t ws_size,
                              hipStream_t stream) {
  const float* feat_3 = (const float*)d_in[1];
  const float* feat_4 = (const float*)d_in[2];
  const float* feat_5 = (const float*)d_in[3];
  const float* w_off5 = (const float*)d_in[4];
  const float* w_om5  = (const float*)d_in[5];
  const float* b_om5  = (const float*)d_in[6];
  const float* w_dcn5 = (const float*)d_in[7];
  const float* b_dcn5 = (const float*)d_in[8];
  const float* w_c1   = (const float*)d_in[9];
  const float* w_off4 = (const float*)d_in[10];
  const float* w_om4  = (const float*)d_in[11];
  const float* b_om4  = (const float*)d_in[12];
  const float* w_dcn4 = (const float*)d_in[13];
  const float* b_dcn4 = (const float*)d_in[14];
  const float* w_sa   = (const float*)d_in[15];
  const float* bn_g   = (const float*)d_in[16];
  const float* bn_b   = (const float*)d_in[17];
  const float* bn_m   = (const float*)d_in[18];
  const float* bn_v   = (const float*)d_in[19];
  const float* w_sem  = (const float*)d_in[20];
  const float* gn_g   = (const float*)d_in[21];
  const float* gn_b   = (const float*)d_in[22];
  float* out = (float*)d_out;
  float* ws = (float*)d_ws;

  // ---- workspace (float offsets) ----
  const long long o_Wp    = 0;                       // 2,883,584 f (fp16 weights)
  const long long o_up5   = o_Wp + 2883584;          // 1,048,576 (alias: am/sa/gnst/partials)
  const long long o_off5h = o_up5 + 1048576;         //   524,288 (fp16)
  const long long o_om5   = o_off5h + 524288;        //   884,736
  const long long o_a5    = o_om5 + 884736;          // 1,048,576
  const long long o_f4n   = o_a5 + 1048576;          // 1,048,576
  const long long o_up4   = o_f4n + 1048576;         // 4,194,304 (alias: z64)
  const long long o_off4h = o_up4 + 4194304;         // 2,097,152 (fp16; alias f4a fp16)
  const long long o_om4   = o_off4h + 2097152;       // 3,538,944
  const long long o_sh    = o_om4 + 3538944;         // shared: cat/col/f3c (fp16)

  const long long shAll = 18874368;                  // col4 all-batch (fp16, floats)
  bool allb = ws_size >= (size_t)(o_sh + shAll) * 4;

  h_t* WpH = (h_t*)ws;
  h_t* wp_off5 = WpH;
  h_t* wp_dcn5 = wp_off5 + 262144;
  h_t* wp_c1   = wp_dcn5 + 1179648;
  h_t* wp_om5  = wp_c1 + 262144;
  h_t* wp_off4 = wp_om5 + 1179648;
  h_t* wp_dcn4 = wp_off4 + 262144;
  h_t* wp_om4  = wp_dcn4 + 1179648;
  h_t* wp_sem  = wp_om4 + 1179648;

  float* up5   = ws + o_up5;
  h_t*   off5h = (h_t*)(ws + o_off5h);
  float* om5   = ws + o_om5;
  float* a5    = ws + o_a5;
  float* f4n   = ws + o_f4n;
  float* up4   = ws + o_up4;
  h_t*   off4h = (h_t*)(ws + o_off4h);
  float* om4   = ws + o_om4;
  h_t*   shH   = (h_t*)(ws + o_sh);
  h_t*   f4aH  = off4h;             // alias (off4 dead after mconv om4)
  float* z64   = up4;               // alias (up4 dead after col4 build)
  float* am    = up5;               // alias (up5 dead after col5 build)
  float* sa    = am + 131072;
  float* gnst  = sa + 65536;
  float2* gnpart = (float2*)(gnst + 256);  // 65536 float2 = 131072 floats

  dim3 blk(256);

  // ---- weight prep (fp16 hi/lo, swizzled; om convs tap-major) ----
  prep_w_kernel<0><<<cdiv(512LL * 512, 256), blk, 0, stream>>>(w_off5, wp_off5, 256, 512);
  prep_w_kernel<0><<<cdiv(512LL * 2304, 256), blk, 0, stream>>>(w_dcn5, wp_dcn5, 256, 2304);
  prep_w_kernel<0><<<cdiv(512LL * 512, 256), blk, 0, stream>>>(w_c1, wp_c1, 256, 512);
  prep_w_kernel<1><<<cdiv(512LL * 2304, 256), blk, 0, stream>>>(w_om5, wp_om5, 216, 2304);
  prep_w_kernel<0><<<cdiv(512LL * 512, 256), blk, 0, stream>>>(w_off4, wp_off4, 256, 512);
  prep_w_kernel<0><<<cdiv(512LL * 2304, 256), blk, 0, stream>>>(w_dcn4, wp_dcn4, 256, 2304);
  prep_w_kernel<1><<<cdiv(512LL * 2304, 256), blk, 0, stream>>>(w_om4, wp_om4, 216, 2304);
  prep_w_kernel<0><<<cdiv(512LL * 512, 256), blk, 0, stream>>>(w_sem, wp_sem, 256, 512);

  // ---- stage A (32x32, HW=1024) ----
  upsample2x_q_kernel<5><<<1024, blk, 0, stream>>>(feat_5, up5, 256);
  concat_a_kernel<float><<<cdiv(4LL * 256 * 1024, 256), blk, 0, stream>>>(
      feat_4, shH, 256, 512, 1024);
  concat_bq_kernel<<<cdiv(4LL * 64 * 1024, 256), blk, 0, stream>>>(
      up5, shH, 256, 256, 1024, 2.f);
  mgemm_kernel<0, 2, 0><<<dim3(16, 2, 4), blk, 0, stream>>>(
      wp_off5, shH, off5h, nullptr, 256, 1024, 512, 512LL * 1024, 256LL * 1024);
  mconv_kernel<5><<<dim3(16, 2, 4), blk, 0, stream>>>(wp_om5, off5h, om5, b_om5, 1024);
  dcn_col_kernel<5><<<dim3(4, 72, 4), blk, 0, stream>>>(up5, om5, shH, 0);
  mgemm32_kernel<0><<<dim3(32, 2, 4), blk, 0, stream>>>(
      wp_dcn5, shH, a5, b_dcn5, 1024, 2304, 2304LL * 1024, 256LL * 1024);
  concat_h_kernel<float><<<cdiv(4LL * 512 * 1024, 256), blk, 0, stream>>>(
      a5, feat_4, shH, 256, 256, 1024, 1.f);
  mgemm_kernel<0, 0, 1><<<dim3(16, 2, 4), blk, 0, stream>>>(
      wp_c1, shH, f4n, nullptr, 256, 1024, 512, 512LL * 1024, 256LL * 1024);

  // ---- stage B (64x64, HW=4096) ----
  upsample2x_q_kernel<6><<<4096, blk, 0, stream>>>(f4n, up4, 256);
  concat_a_kernel<float><<<cdiv(4LL * 256 * 4096, 256), blk, 0, stream>>>(
      feat_3, shH, 256, 512, 4096);
  concat_bq_kernel<<<cdiv(4LL * 64 * 4096, 256), blk, 0, stream>>>(
      up4, shH, 256, 256, 4096, 2.f);
  mgemm_kernel<0, 2, 0><<<dim3(64, 2, 4), blk, 0, stream>>>(
      wp_off4, shH, off4h, nullptr, 256, 4096, 512, 512LL * 4096, 256LL * 4096);
  mconv_kernel<6><<<dim3(64, 2, 4), blk, 0, stream>>>(wp_om4, off4h, om4, b_om4, 4096);
  if (allb) {
    dcn_col_kernel<6><<<dim3(16, 72, 4), blk, 0, stream>>>(up4, om4, shH, 0);
    mgemm32_kernel<1><<<dim3(128, 2, 4), blk, 0, stream>>>(
        wp_dcn4, shH, f4aH, b_dcn4, 4096, 2304, 2304LL * 4096, 256LL * 4096);
  } else {
    for (int b = 0; b < 4; b++) {
      dcn_col_kernel<6><<<dim3(16, 72, 1), blk, 0, stream>>>(up4, om4, shH, b);
      mgemm32_kernel<1><<<dim3(128, 2, 1), blk, 0, stream>>>(
          wp_dcn4, shH, f4aH + (long long)b * 1048576, b_dcn4, 4096, 2304, 0, 0);
    }
  }
  concat_h_kernel<h_t><<<cdiv(4LL * 512 * 4096, 256), blk, 0, stream>>>(
      f4aH, feat_3, shH, 256, 256, 4096, 1.f);

  // ---- SEM head ----
  avgmax_kernel<<<1024, blk, 0, stream>>>(shH, am);
  sa_kernel<<<1024, dim3(64), 0, stream>>>(am, w_sa, bn_g, bn_b, bn_m, bn_v, sa);
  mgemm_kernel<0, 0, 1><<<dim3(64, 2, 4), blk, 0, stream>>>(
      wp_sem, shH, z64, nullptr, 256, 4096, 512, 512LL * 4096, 256LL * 4096);
  gn_partials_kernel<<<65536, blk, 0, stream>>>(z64, sa, gnpart);
  gn_reduce_kernel<<<128, blk, 0, stream>>>(gnpart, gnst);
  gn_apply_fused_kernel<<<16384, blk, 0, stream>>>(z64, sa, gnst, gn_g, gn_b, out);
}

// Round 6
// 690.966 us; speedup vs baseline: 1.3171x; 1.3171x over previous
//
#include <hip/hip_runtime.h>
#include <math.h>

// ============================================================================
// FeatureAlign (2-level DCNv2 pyramid + SEM head).
// R4: GN y round-trip eliminated (gn_partials + gn_apply_fused recompute).
// R5: dcn_col gather vectorized via channel-quad x layout [c/4][HW][4].
// R6: mconv barrier-free/LDS-free (offset GEMM stores transposed fp16).
// R7 (REVERTED): barrier-free DCN GEMM — scattered B loads, 120us.
// R8 (REVERTED): 32N tile — halved MFMA/barrier, 205us. Conflict counter is an
//     aggregate artifact (same 1.416e7 across unrelated kernels).
// R9: back to R6 structure; mgemm double-buffered LDS -> ONE barrier per
//     K-chunk (was 2), prefetch next chunk into regs under compute. Same MFMA
//     order (bitwise-identical). concat_bq fused into upsample (quad + fp16
//     concat half in one pass, -16.8MB re-read, -2 dispatches).
// ============================================================================

typedef _Float16 h_t;
typedef _Float16 h2 __attribute__((ext_vector_type(2)));
typedef _Float16 h4 __attribute__((ext_vector_type(4)));
typedef _Float16 h8 __attribute__((ext_vector_type(8)));
typedef float f4 __attribute__((ext_vector_type(4)));

static inline int cdiv(long long a, long long b) { return (int)((a + b - 1) / b); }

// ---------------- weight prep: fp32 [M][K] -> swizzled fp16 hi/lo ----------------
// layout: idx = ((mblk*(K/32)+c)*2 + s)*4096 + m*32 + k   (mblk: 128-row block)
// PERM=1: k-space permuted tap-major: k' = tap*256 + ch, source k = ch*9 + tap.
template <int PERM>
__global__ void prep_w_kernel(const float* __restrict__ W, h_t* __restrict__ Wp,
                              int M, int K) {
  long long idx = (long long)blockIdx.x * 256 + threadIdx.x;
  if (idx >= 512LL * K) return;
  int within = (int)(idx & 4095);
  int m = within >> 5, k = within & 31;
  long long t2 = idx >> 12;
  int s = (int)(t2 & 1);
  long long t3 = t2 >> 1;
  int nck = K >> 5;
  int c = (int)(t3 % nck), mblk = (int)(t3 / nck);
  int gm = mblk * 128 + m, gk = c * 32 + k;
  if (PERM) gk = (gk & 255) * 9 + (gk >> 8);
  float f = (gm < M) ? W[(long long)gm * K + gk] : 0.f;
  h_t hi = (h_t)f;
  Wp[idx] = s ? (h_t)(f - (float)hi) : hi;
}

// ---------------- bilinear 2x upsample -> quad layout + fp16 concat half ----------------
// in: [256 quads][IH][IW] f32. outq: [q][OH][OW][4] f32.
// outc: cat buffer [b][512][OHW] fp16; writes channels 256..511 scaled.
template <int LOGOW>
__global__ void upsample2x_qc_kernel(const float* __restrict__ in, float* __restrict__ outq,
                                     h_t* __restrict__ outc, float scale) {
  const int OW = 1 << LOGOW, OHW = OW * OW, IW = OW >> 1;
  long long idx = (long long)blockIdx.x * 256 + threadIdx.x;
  if (idx >= 256LL * OHW) return;
  int p = (int)(idx & (OHW - 1));
  int qg = (int)(idx >> (2 * LOGOW));
  int oh = p >> LOGOW, ow = p & (OW - 1);
  int iy = oh >> 1, ix = ow >> 1;
  int iy2 = (oh & 1) ? min(iy + 1, IW - 1) : max(iy - 1, 0);
  int ix2 = (ow & 1) ? min(ix + 1, IW - 1) : max(ix - 1, 0);
  const float* pb = in + (long long)qg * 4 * IW * IW;
  f4 o;
#pragma unroll
  for (int j = 0; j < 4; ++j) {
    const float* pc = pb + (long long)j * IW * IW;
    o[j] = 0.5625f * pc[iy * IW + ix] + 0.1875f * (pc[iy * IW + ix2] + pc[iy2 * IW + ix])
         + 0.0625f * pc[iy2 * IW + ix2];
  }
  *(f4*)(outq + idx * 4) = o;
  int b = qg >> 6, ql = qg & 63;
  h_t* oc = outc + ((long long)b * 512 + 256 + ql * 4) * OHW + p;
  oc[0]                = (h_t)(scale * o[0]);
  oc[(long long)OHW]       = (h_t)(scale * o[1]);
  oc[(long long)2 * OHW]   = (h_t)(scale * o[2]);
  oc[(long long)3 * OHW]   = (h_t)(scale * o[3]);
}

// ---------------- channel concat -> fp16: out[b] = [A[b], scale*B[b]] ----------------
template <typename TA>
__global__ void concat_h_kernel(const TA* __restrict__ A, const float* __restrict__ Bp,
                                h_t* __restrict__ out, int C1, int C2, int HW, float scale) {
  long long idx = (long long)blockIdx.x * blockDim.x + threadIdx.x;
  long long total = 4LL * (C1 + C2) * HW;
  if (idx >= total) return;
  int p = (int)(idx % HW);
  long long t = idx / HW;
  int c = (int)(t % (C1 + C2));
  int b = (int)(t / (C1 + C2));
  float v;
  if (c < C1) v = (float)A[((long long)b * C1 + c) * HW + p];
  else        v = scale * Bp[((long long)b * C2 + (c - C1)) * HW + p];
  out[idx] = (h_t)v;
}

// ---------------- concat A-half only: out[b][0..C1) = A ----------------
template <typename TA>
__global__ void concat_a_kernel(const TA* __restrict__ A, h_t* __restrict__ out,
                                int C1, int Ctot, int HW) {
  long long idx = (long long)blockIdx.x * 256 + threadIdx.x;
  long long total = 4LL * C1 * HW;
  if (idx >= total) return;
  int p = (int)(idx % HW);
  long long t = idx / HW;
  int c = (int)(t % C1);
  int b = (int)(t / C1);
  out[((long long)b * Ctot + c) * HW + p] = (h_t)(float)A[((long long)b * C1 + c) * HW + p];
}

// ---------------- MFMA GEMM (double-buffered LDS, 1 barrier/chunk) ----------------
// Wp: swizzled fp16 (prep_w). B: fp16 [K][N]. Block tile 128M x 64N, 4 waves
// (2x2), wave tile 64x32. TWO=1: W_hi+W_lo split.
// OUTH: 0 = f32 [M][N]; 1 = fp16 [M][N]; 2 = fp16 TRANSPOSED [N][256] (h4 st).
template <int RELU, int OUTH, int TWO>
__global__ __launch_bounds__(256) void mgemm_kernel(
    const h_t* __restrict__ Wp, const h_t* __restrict__ B, void* __restrict__ Cv,
    const float* __restrict__ bias, int Mstore, int N, int K,
    long long sB, long long sC) {
  __shared__ __align__(16) h_t Ah[2][128 * 40];
  __shared__ __align__(16) h_t Al[2][TWO ? 128 * 40 : 8];
  __shared__ __align__(16) h_t Bs[2][64 * 40];
  const int tid = threadIdx.x;
  const int bn = blockIdx.x * 64;
  const int mblk = blockIdx.y;
  const int z = blockIdx.z;
  const h_t* Bb = B + (long long)z * sB;
  const int nck = K >> 5;
  const h_t* Wt = Wp + (long long)mblk * nck * 8192 +
                  (TWO ? (tid << 5) : ((tid >> 1) << 5) + ((tid & 1) << 4));
  const int wid = tid >> 6, lane = tid & 63;
  const int wm = (wid >> 1) * 64, wn = (wid & 1) * 32;
  const int l15 = lane & 15, q = lane >> 4;
  f4 acc[4][2] = {};
  const int adst = TWO ? (tid & 127) * 40 : (tid >> 1) * 40 + ((tid & 1) << 4);
  const int kp = tid >> 4, ngf = tid & 15;
  const int bdst = ngf * 4 * 40 + kp * 2;
  h8 ra[4];
  h4 rb0, rb1;
  // prologue: load chunk 0 into regs
  {
    const h_t* asrc = Wt;
    if (TWO) {
#pragma unroll
      for (int i = 0; i < 4; ++i) ra[i] = *(const h8*)(asrc + i * 8);
    } else {
      ra[0] = *(const h8*)(asrc);
      ra[1] = *(const h8*)(asrc + 8);
    }
    const h_t* bsrc = Bb + (long long)(kp * 2) * N + bn + ngf * 4;
    rb0 = *(const h4*)bsrc;
    rb1 = *(const h4*)(bsrc + N);
  }
  for (int c = 0; c < nck; ++c) {
    const int bsel = c & 1;
    // write current chunk regs -> LDS buf[bsel]
    h_t* Ad = (TWO ? (tid >= 128 ? Al[bsel] : Ah[bsel]) : Ah[bsel]) + adst;
    if (TWO) {
#pragma unroll
      for (int i = 0; i < 4; ++i) *(h8*)(Ad + i * 8) = ra[i];
    } else {
      *(h8*)(Ad) = ra[0];
      *(h8*)(Ad + 8) = ra[1];
    }
    h_t* Bd = Bs[bsel] + bdst;
#pragma unroll
    for (int j = 0; j < 4; ++j) {
      h2 v; v.x = rb0[j]; v.y = rb1[j];
      *(h2*)(Bd + j * 40) = v;
    }
    // prefetch next chunk into regs (latency hidden under compute)
    if (c + 1 < nck) {
      const h_t* asrc = Wt + (c + 1) * 8192;
      if (TWO) {
#pragma unroll
        for (int i = 0; i < 4; ++i) ra[i] = *(const h8*)(asrc + i * 8);
      } else {
        ra[0] = *(const h8*)(asrc);
        ra[1] = *(const h8*)(asrc + 8);
      }
      const h_t* bsrc = Bb + (long long)((c + 1) * 32 + kp * 2) * N + bn + ngf * 4;
      rb0 = *(const h4*)bsrc;
      rb1 = *(const h4*)(bsrc + N);
    }
    __syncthreads();  // buf[bsel] ready; prev reads of buf[bsel^1] were done
    h8 bf[2];
#pragma unroll
    for (int nt = 0; nt < 2; ++nt)
      bf[nt] = *(const h8*)(Bs[bsel] + (wn + nt * 16 + l15) * 40 + q * 8);
#pragma unroll
    for (int mt = 0; mt < 4; ++mt) {
      const int ro = (wm + mt * 16 + l15) * 40 + q * 8;
      h8 ahi = *(const h8*)(Ah[bsel] + ro);
#pragma unroll
      for (int nt = 0; nt < 2; ++nt)
        acc[mt][nt] = __builtin_amdgcn_mfma_f32_16x16x32_f16(ahi, bf[nt], acc[mt][nt], 0, 0, 0);
      if (TWO) {
        h8 alo = *(const h8*)(Al[bsel] + ro);
#pragma unroll
        for (int nt = 0; nt < 2; ++nt)
          acc[mt][nt] = __builtin_amdgcn_mfma_f32_16x16x32_f16(alo, bf[nt], acc[mt][nt], 0, 0, 0);
      }
    }
    // no trailing barrier: next iteration writes the OTHER buffer; the single
    // barrier per iteration collectively orders reads-before-overwrite.
  }
#pragma unroll
  for (int mt = 0; mt < 4; ++mt)
#pragma unroll
    for (int nt = 0; nt < 2; ++nt) {
      int n = bn + wn + nt * 16 + l15;
      if (OUTH == 2) {
        int row0 = mblk * 128 + wm + mt * 16 + q * 4;
        if (row0 + 3 < Mstore) {
          h4 hv;
#pragma unroll
          for (int r = 0; r < 4; ++r) {
            float v = acc[mt][nt][r] + (bias ? bias[row0 + r] : 0.f);
            if (RELU) v = fmaxf(v, 0.f);
            hv[r] = (h_t)v;
          }
          *(h4*)((h_t*)Cv + (long long)z * sC + (long long)n * 256 + row0) = hv;
        }
      } else {
#pragma unroll
        for (int r = 0; r < 4; ++r) {
          int row = mblk * 128 + wm + mt * 16 + q * 4 + r;
          if (row < Mstore) {
            float v = acc[mt][nt][r] + (bias ? bias[row] : 0.f);
            if (RELU) v = fmaxf(v, 0.f);
            if (OUTH) ((h_t*)Cv)[(long long)z * sC + (long long)row * N + n] = (h_t)v;
            else      ((float*)Cv)[(long long)z * sC + (long long)row * N + n] = v;
          }
        }
      }
    }
}

// ---------------- conv3x3 as MFMA implicit GEMM, barrier-free ----------------
template <int LOGW>
__global__ __launch_bounds__(256) void mconv_kernel(
    const h_t* __restrict__ Wp, const h_t* __restrict__ OffT, float* __restrict__ Cf,
    const float* __restrict__ bias, int HW) {
  const int W = 1 << LOGW, H = HW >> LOGW;
  const int tid = threadIdx.x;
  const int p0 = blockIdx.x * 64;
  const int mblk = blockIdx.y;
  const int z = blockIdx.z;
  const h_t* Ot = OffT + (long long)z * HW * 256;
  const h_t* Wb = Wp + (long long)mblk * 72 * 8192;
  const int wid = tid >> 6, lane = tid & 63;
  const int wm = (wid >> 1) * 64, wn = (wid & 1) * 32;
  const int l15 = lane & 15, q = lane >> 4;
  const int aoff = (wm + l15) * 32 + q * 8;
  f4 acc[4][2] = {};
  int py[2], px[2];
#pragma unroll
  for (int nt = 0; nt < 2; ++nt) {
    int p = p0 + wn + nt * 16 + l15;
    py[nt] = p >> LOGW;
    px[nt] = p & (W - 1);
  }
  for (int tap = 0; tap < 9; ++tap) {
    const int dy = tap / 3 - 1, dx = tap - (tap / 3) * 3 - 1;
    const h_t* bsrc[2];
    bool bok[2];
#pragma unroll
    for (int nt = 0; nt < 2; ++nt) {
      int sy = py[nt] + dy, sx = px[nt] + dx;
      bok[nt] = (sy >= 0) & (sy < H) & (sx >= 0) & (sx < W);
      int sp = bok[nt] ? (sy * W + sx) : 0;
      bsrc[nt] = Ot + (long long)sp * 256 + q * 8;
    }
#pragma unroll 2
    for (int c2 = 0; c2 < 8; ++c2) {
      const int c = tap * 8 + c2;
      h8 bf[2];
#pragma unroll
      for (int nt = 0; nt < 2; ++nt) {
        h8 v = {};
        if (bok[nt]) v = *(const h8*)(bsrc[nt] + c2 * 32);
        bf[nt] = v;
      }
      const h_t* aw = Wb + (long long)c * 8192 + aoff;
#pragma unroll
      for (int mt = 0; mt < 4; ++mt) {
        h8 af = *(const h8*)(aw + mt * 512);
#pragma unroll
        for (int nt = 0; nt < 2; ++nt)
          acc[mt][nt] = __builtin_amdgcn_mfma_f32_16x16x32_f16(af, bf[nt], acc[mt][nt], 0, 0, 0);
      }
    }
  }
  float* Cb = Cf + (long long)z * 216 * HW;
#pragma unroll
  for (int mt = 0; mt < 4; ++mt)
#pragma unroll
    for (int nt = 0; nt < 2; ++nt) {
      int n = p0 + wn + nt * 16 + l15;
#pragma unroll
      for (int r = 0; r < 4; ++r) {
        int row = mblk * 128 + wm + mt * 16 + q * 4 + r;
        if (row < 216)
          Cb[(long long)row * HW + n] = acc[mt][nt][r] + bias[row];
      }
    }
}

// ---------------- DCNv2 column build (fp16 out): col[bz][(g*32+c)*9+k][p] ----------------
// x in channel-quad layout [c/4][HW][4]: one dwordx4 per corner per 4 channels.
template <int LOGW>
__global__ __launch_bounds__(256) void dcn_col_kernel(
    const float* __restrict__ x, const float* __restrict__ om,
    h_t* __restrict__ col, int b0) {
  const int W = 1 << LOGW, H = W, HW = W * W;
  int p = blockIdx.x * 256 + threadIdx.x;
  int gk = blockIdx.y;           // 0..71
  int g = gk / 9, k9 = gk - g * 9;
  int bz = blockIdx.z;
  int b = b0 + bz;
  int h = p >> LOGW, wc = p & (W - 1);
  const float* omb = om + (long long)b * 216 * HW;
  float offy = omb[(long long)gk * HW + p];
  float offx = omb[(long long)(72 + gk) * HW + p];
  float mraw = omb[(long long)(144 + gk) * HW + p];
  float mask = 1.f / (1.f + expf(-mraw));
  float y = (float)h + (float)(k9 / 3 - 1) + offy;
  float xx = (float)wc + (float)(k9 % 3 - 1) + offx;
  float y0f = floorf(y), x0f = floorf(xx);
  int y0 = (int)y0f, x0 = (int)x0f;
  float fy = y - y0f, fx = xx - x0f;
  float w00 = (1.f - fy) * (1.f - fx), w01 = (1.f - fy) * fx;
  float w10 = fy * (1.f - fx), w11 = fy * fx;
  bool iy0 = (y0 >= 0) & (y0 < H), iy1 = (y0 + 1 >= 0) & (y0 + 1 < H);
  bool ix0 = (x0 >= 0) & (x0 < W), ix1 = (x0 + 1 >= 0) & (x0 + 1 < W);
  w00 = (iy0 & ix0) ? w00 : 0.f;
  w01 = (iy0 & ix1) ? w01 : 0.f;
  w10 = (iy1 & ix0) ? w10 : 0.f;
  w11 = (iy1 & ix1) ? w11 : 0.f;
  int y0c = min(max(y0, 0), H - 1), y1c = min(max(y0 + 1, 0), H - 1);
  int x0c = min(max(x0, 0), W - 1), x1c = min(max(x0 + 1, 0), W - 1);
  int i00 = y0c * W + x0c, i01 = y0c * W + x1c, i10 = y1c * W + x0c, i11 = y1c * W + x1c;
  const float* xb = x + ((long long)b * 256 + g * 32) * HW;
  h_t* cb = col + ((long long)bz * 2304 + (long long)(g * 32) * 9 + k9) * HW + p;
#pragma unroll 1
  for (int qd = 0; qd < 8; qd += 2) {
    f4 a00[2], a01[2], a10[2], a11[2];
#pragma unroll
    for (int u = 0; u < 2; ++u) {
      const float* xq = xb + (long long)(qd + u) * HW * 4;
      a00[u] = *(const f4*)(xq + i00 * 4);
      a01[u] = *(const f4*)(xq + i01 * 4);
      a10[u] = *(const f4*)(xq + i10 * 4);
      a11[u] = *(const f4*)(xq + i11 * 4);
    }
#pragma unroll
    for (int u = 0; u < 2; ++u)
#pragma unroll
      for (int j = 0; j < 4; ++j) {
        float v = w00 * a00[u][j] + w01 * a01[u][j] + w10 * a10[u][j] + w11 * a11[u][j];
        cb[(long long)((qd + u) * 4 + j) * 9 * HW] = (h_t)(v * mask);
      }
  }
}

// ---------------- channel avg/max of up2x(f3c fp16) at 128x128 ----------------
__global__ void avgmax_kernel(const h_t* __restrict__ f3c, float* __restrict__ am) {
  int tid = threadIdx.x;
  int P = blockIdx.x * 64 + (tid >> 2);   // global pixel 0..65535
  int cq = tid & 3;
  int b = P >> 14, p = P & 16383;
  int oh = p >> 7, ow = p & 127;
  int iy = oh >> 1, ix = ow >> 1;
  int iy2 = (oh & 1) ? min(iy + 1, 63) : max(iy - 1, 0);
  int ix2 = (ow & 1) ? min(ix + 1, 63) : max(ix - 1, 0);
  int i00 = iy * 64 + ix, i01 = iy * 64 + ix2, i10 = iy2 * 64 + ix, i11 = iy2 * 64 + ix2;
  const h_t* base = f3c + (long long)b * 512 * 4096 + (long long)cq * 4096;
  float sum = 0.f, mx = -3.4e38f;
  for (int c = 0; c < 128; c++) {
    const h_t* pc = base + (long long)c * 4 * 4096;
    float v = 0.5625f * (float)pc[i00] + 0.1875f * ((float)pc[i01] + (float)pc[i10])
            + 0.0625f * (float)pc[i11];
    sum += v;
    mx = fmaxf(mx, v);
  }
  sum += __shfl_xor(sum, 1); sum += __shfl_xor(sum, 2);
  mx = fmaxf(mx, __shfl_xor(mx, 1)); mx = fmaxf(mx, __shfl_xor(mx, 2));
  if (cq == 0) {
    am[(long long)b * 2 * 16384 + p] = sum * (1.f / 512.f);
    am[(long long)b * 2 * 16384 + 16384 + p] = mx;
  }
}

// ---------------- conv7x7 (2->1) + BN + sigmoid -> sa ----------------
__global__ void sa_kernel(const float* __restrict__ am, const float* __restrict__ w_sa,
                          const float* __restrict__ bn_g, const float* __restrict__ bn_b,
                          const float* __restrict__ bn_m, const float* __restrict__ bn_v,
                          float* __restrict__ sa) {
  int idx = blockIdx.x * 64 + threadIdx.x; // 4*16384, 64-thread blocks
  int b = idx >> 14, p = idx & 16383;
  int oh = p >> 7, ow = p & 127;
  float acc = 0.f;
  for (int ci = 0; ci < 2; ci++) {
    const float* base = am + ((long long)b * 2 + ci) * 16384;
    for (int dy = 0; dy < 7; dy++) {
      int yy = oh + dy - 3;
      if (yy < 0 || yy > 127) continue;
      for (int dx = 0; dx < 7; dx++) {
        int xx = ow + dx - 3;
        if (xx < 0 || xx > 127) continue;
        acc += w_sa[ci * 49 + dy * 7 + dx] * base[yy * 128 + xx];
      }
    }
  }
  float a = (acc - bn_m[0]) * rsqrtf(bn_v[0] + 1e-5f);
  a = a * bn_g[0] + bn_b[0];
  sa[idx] = 1.f / (1.f + expf(-a));
}

// ---------------- GN stage-1: y = (1+sa)*up2x(z), partial sums only ----------------
__global__ __launch_bounds__(256) void gn_partials_kernel(
    const float* __restrict__ z, const float* __restrict__ sa,
    float2* __restrict__ partials) {
  long long idx = (long long)blockIdx.x * 256 + threadIdx.x; // 16,777,216
  int ow = (int)(idx & 127);
  long long t = idx >> 7;
  int oh = (int)(t & 127);
  t >>= 7;
  int c = (int)(t & 255);
  int b = (int)(t >> 8);
  int iy = oh >> 1, ix = ow >> 1;
  int iy2 = (oh & 1) ? min(iy + 1, 63) : max(iy - 1, 0);
  int ix2 = (ow & 1) ? min(ix + 1, 63) : max(ix - 1, 0);
  const float* zp = z + (long long)(b * 256 + c) * 4096;
  float v = 0.5625f * zp[iy * 64 + ix] + 0.1875f * (zp[iy * 64 + ix2] + zp[iy2 * 64 + ix])
          + 0.0625f * zp[iy2 * 64 + ix2];
  float s = sa[((long long)b << 14) + (oh << 7) + ow];
  float y = v * (1.f + s);
  float ps = y, pss = y * y;
#pragma unroll
  for (int off = 32; off > 0; off >>= 1) {
    ps += __shfl_down(ps, off);
    pss += __shfl_down(pss, off);
  }
  __shared__ float rs[2][4];
  int lane = threadIdx.x & 63, wv = threadIdx.x >> 6;
  if (lane == 0) { rs[0][wv] = ps; rs[1][wv] = pss; }
  __syncthreads();
  if (threadIdx.x == 0) {
    float2 pr;
    pr.x = rs[0][0] + rs[0][1] + rs[0][2] + rs[0][3];
    pr.y = rs[1][0] + rs[1][1] + rs[1][2] + rs[1][3];
    partials[blockIdx.x] = pr;
  }
}

// ---------------- GN stage-2: reduce 512 partials per (b,g) -> mu, rstd ----------------
__global__ __launch_bounds__(256) void gn_reduce_kernel(const float2* __restrict__ partials,
                                                        float* __restrict__ stats) {
  int bg = blockIdx.x; // 0..127
  int b = bg >> 5, g = bg & 31;
  int base = b * 16384 + g * 512;
  float2 p0 = partials[base + threadIdx.x];
  float2 p1 = partials[base + 256 + threadIdx.x];
  float s = p0.x + p1.x, ss = p0.y + p1.y;
#pragma unroll
  for (int off = 32; off > 0; off >>= 1) {
    s += __shfl_down(s, off);
    ss += __shfl_down(ss, off);
  }
  __shared__ float rs[2][4];
  int lane = threadIdx.x & 63, wv = threadIdx.x >> 6;
  if (lane == 0) { rs[0][wv] = s; rs[1][wv] = ss; }
  __syncthreads();
  if (threadIdx.x == 0) {
    float S = rs[0][0] + rs[0][1] + rs[0][2] + rs[0][3];
    float SS = rs[1][0] + rs[1][1] + rs[1][2] + rs[1][3];
    float n = 8.f * 16384.f;
    float mu = S / n;
    float var = SS / n - mu * mu;
    stats[bg * 2] = mu;
    stats[bg * 2 + 1] = rsqrtf(var + 1e-5f);
  }
}

// ---------------- GN stage-3: recompute y, normalize, store ----------------
__global__ __launch_bounds__(256) void gn_apply_fused_kernel(
    const float* __restrict__ z, const float* __restrict__ sa,
    const float* __restrict__ stats, const float* __restrict__ gg,
    const float* __restrict__ gb, float* __restrict__ out) {
  long long i4 = (long long)blockIdx.x * 256 + threadIdx.x; // 4,194,304 float4s
  long long e = i4 << 2;
  int ow0 = (int)(e & 127);
  int oh = (int)((e >> 7) & 127);
  int c = (int)((e >> 14) & 255);
  int b = (int)(e >> 22);
  int bg = b * 32 + (c >> 3);
  float mu = stats[bg * 2], rstd = stats[bg * 2 + 1];
  float sc = rstd * gg[c];
  float sh = gb[c] - mu * sc;
  int iy = oh >> 1;
  int iy2 = (oh & 1) ? min(iy + 1, 63) : max(iy - 1, 0);
  const float* zp = z + (long long)(b * 256 + c) * 4096;
  f4 sv = *(const f4*)(sa + (((long long)b << 14) + (oh << 7) + ow0));
  f4 o;
#pragma unroll
  for (int j = 0; j < 4; ++j) {
    int ow = ow0 + j;
    int ix = ow >> 1;
    int ix2 = (ow & 1) ? min(ix + 1, 63) : max(ix - 1, 0);
    float v = 0.5625f * zp[iy * 64 + ix] + 0.1875f * (zp[iy * 64 + ix2] + zp[iy2 * 64 + ix])
            + 0.0625f * zp[iy2 * 64 + ix2];
    float y = v * (1.f + sv[j]);
    o[j] = y * sc + sh;
  }
  *(f4*)(out + e) = o;
}

// ============================================================================

extern "C" void kernel_launch(void* const* d_in, const int* in_sizes, int n_in,
                              void* d_out, int out_size, void* d_ws, size_t ws_size,
                              hipStream_t stream) {
  const float* feat_3 = (const float*)d_in[1];
  const float* feat_4 = (const float*)d_in[2];
  const float* feat_5 = (const float*)d_in[3];
  const float* w_off5 = (const float*)d_in[4];
  const float* w_om5  = (const float*)d_in[5];
  const float* b_om5  = (const float*)d_in[6];
  const float* w_dcn5 = (const float*)d_in[7];
  const float* b_dcn5 = (const float*)d_in[8];
  const float* w_c1   = (const float*)d_in[9];
  const float* w_off4 = (const float*)d_in[10];
  const float* w_om4  = (const float*)d_in[11];
  const float* b_om4  = (const float*)d_in[12];
  const float* w_dcn4 = (const float*)d_in[13];
  const float* b_dcn4 = (const float*)d_in[14];
  const float* w_sa   = (const float*)d_in[15];
  const float* bn_g   = (const float*)d_in[16];
  const float* bn_b   = (const float*)d_in[17];
  const float* bn_m   = (const float*)d_in[18];
  const float* bn_v   = (const float*)d_in[19];
  const float* w_sem  = (const float*)d_in[20];
  const float* gn_g   = (const float*)d_in[21];
  const float* gn_b   = (const float*)d_in[22];
  float* out = (float*)d_out;
  float* ws = (float*)d_ws;

  // ---- workspace (float offsets) ----
  const long long o_Wp    = 0;                       // 2,883,584 f (fp16 weights)
  const long long o_up5   = o_Wp + 2883584;          // 1,048,576 (alias: am/sa/gnst/partials)
  const long long o_off5h = o_up5 + 1048576;         //   524,288 (fp16)
  const long long o_om5   = o_off5h + 524288;        //   884,736
  const long long o_a5    = o_om5 + 884736;          // 1,048,576
  const long long o_f4n   = o_a5 + 1048576;          // 1,048,576
  const long long o_up4   = o_f4n + 1048576;         // 4,194,304 (alias: z64)
  const long long o_off4h = o_up4 + 4194304;         // 2,097,152 (fp16; alias f4a fp16)
  const long long o_om4   = o_off4h + 2097152;       // 3,538,944
  const long long o_sh    = o_om4 + 3538944;         // shared: cat/col/f3c (fp16)

  const long long shAll = 18874368;                  // col4 all-batch (fp16, floats)
  bool allb = ws_size >= (size_t)(o_sh + shAll) * 4;

  h_t* WpH = (h_t*)ws;
  h_t* wp_off5 = WpH;
  h_t* wp_dcn5 = wp_off5 + 262144;
  h_t* wp_c1   = wp_dcn5 + 1179648;
  h_t* wp_om5  = wp_c1 + 262144;
  h_t* wp_off4 = wp_om5 + 1179648;
  h_t* wp_dcn4 = wp_off4 + 262144;
  h_t* wp_om4  = wp_dcn4 + 1179648;
  h_t* wp_sem  = wp_om4 + 1179648;

  float* up5   = ws + o_up5;
  h_t*   off5h = (h_t*)(ws + o_off5h);
  float* om5   = ws + o_om5;
  float* a5    = ws + o_a5;
  float* f4n   = ws + o_f4n;
  float* up4   = ws + o_up4;
  h_t*   off4h = (h_t*)(ws + o_off4h);
  float* om4   = ws + o_om4;
  h_t*   shH   = (h_t*)(ws + o_sh);
  h_t*   f4aH  = off4h;             // alias (off4 dead after mconv om4)
  float* z64   = up4;               // alias (up4 dead after col4 build)
  float* am    = up5;               // alias (up5 dead after col5 build)
  float* sa    = am + 131072;
  float* gnst  = sa + 65536;
  float2* gnpart = (float2*)(gnst + 256);  // 65536 float2 = 131072 floats

  dim3 blk(256);

  // ---- weight prep (fp16 hi/lo, swizzled; om convs tap-major) ----
  prep_w_kernel<0><<<cdiv(512LL * 512, 256), blk, 0, stream>>>(w_off5, wp_off5, 256, 512);
  prep_w_kernel<0><<<cdiv(512LL * 2304, 256), blk, 0, stream>>>(w_dcn5, wp_dcn5, 256, 2304);
  prep_w_kernel<0><<<cdiv(512LL * 512, 256), blk, 0, stream>>>(w_c1, wp_c1, 256, 512);
  prep_w_kernel<1><<<cdiv(512LL * 2304, 256), blk, 0, stream>>>(w_om5, wp_om5, 216, 2304);
  prep_w_kernel<0><<<cdiv(512LL * 512, 256), blk, 0, stream>>>(w_off4, wp_off4, 256, 512);
  prep_w_kernel<0><<<cdiv(512LL * 2304, 256), blk, 0, stream>>>(w_dcn4, wp_dcn4, 256, 2304);
  prep_w_kernel<1><<<cdiv(512LL * 2304, 256), blk, 0, stream>>>(w_om4, wp_om4, 216, 2304);
  prep_w_kernel<0><<<cdiv(512LL * 512, 256), blk, 0, stream>>>(w_sem, wp_sem, 256, 512);

  // ---- stage A (32x32, HW=1024) ----
  upsample2x_qc_kernel<5><<<1024, blk, 0, stream>>>(feat_5, up5, shH, 2.f);
  concat_a_kernel<float><<<cdiv(4LL * 256 * 1024, 256), blk, 0, stream>>>(
      feat_4, shH, 256, 512, 1024);
  mgemm_kernel<0, 2, 0><<<dim3(16, 2, 4), blk, 0, stream>>>(
      wp_off5, shH, off5h, nullptr, 256, 1024, 512, 512LL * 1024, 256LL * 1024);
  mconv_kernel<5><<<dim3(16, 2, 4), blk, 0, stream>>>(wp_om5, off5h, om5, b_om5, 1024);
  dcn_col_kernel<5><<<dim3(4, 72, 4), blk, 0, stream>>>(up5, om5, shH, 0);
  mgemm_kernel<1, 0, 1><<<dim3(16, 2, 4), blk, 0, stream>>>(
      wp_dcn5, shH, a5, b_dcn5, 256, 1024, 2304, 2304LL * 1024, 256LL * 1024);
  concat_h_kernel<float><<<cdiv(4LL * 512 * 1024, 256), blk, 0, stream>>>(
      a5, feat_4, shH, 256, 256, 1024, 1.f);
  mgemm_kernel<0, 0, 1><<<dim3(16, 2, 4), blk, 0, stream>>>(
      wp_c1, shH, f4n, nullptr, 256, 1024, 512, 512LL * 1024, 256LL * 1024);

  // ---- stage B (64x64, HW=4096) ----
  upsample2x_qc_kernel<6><<<4096, blk, 0, stream>>>(f4n, up4, shH, 2.f);
  concat_a_kernel<float><<<cdiv(4LL * 256 * 4096, 256), blk, 0, stream>>>(
      feat_3, shH, 256, 512, 4096);
  mgemm_kernel<0, 2, 0><<<dim3(64, 2, 4), blk, 0, stream>>>(
      wp_off4, shH, off4h, nullptr, 256, 4096, 512, 512LL * 4096, 256LL * 4096);
  mconv_kernel<6><<<dim3(64, 2, 4), blk, 0, stream>>>(wp_om4, off4h, om4, b_om4, 4096);
  if (allb) {
    dcn_col_kernel<6><<<dim3(16, 72, 4), blk, 0, stream>>>(up4, om4, shH, 0);
    mgemm_kernel<1, 1, 1><<<dim3(64, 2, 4), blk, 0, stream>>>(
        wp_dcn4, shH, f4aH, b_dcn4, 256, 4096, 2304, 2304LL * 4096, 256LL * 4096);
  } else {
    for (int b = 0; b < 4; b++) {
      dcn_col_kernel<6><<<dim3(16, 72, 1), blk, 0, stream>>>(up4, om4, shH, b);
      mgemm_kernel<1, 1, 1><<<dim3(64, 2, 1), blk, 0, stream>>>(
          wp_dcn4, shH, f4aH + (long long)b * 1048576, b_dcn4, 256, 4096, 2304, 0, 0);
    }
  }
  concat_h_kernel<h_t><<<cdiv(4LL * 512 * 4096, 256), blk, 0, stream>>>(
      f4aH, feat_3, shH, 256, 256, 4096, 1.f);

  // ---- SEM head ----
  avgmax_kernel<<<1024, blk, 0, stream>>>(shH, am);
  sa_kernel<<<1024, dim3(64), 0, stream>>>(am, w_sa, bn_g, bn_b, bn_m, bn_v, sa);
  mgemm_kernel<0, 0, 1><<<dim3(64, 2, 4), blk, 0, stream>>>(
      wp_sem, shH, z64, nullptr, 256, 4096, 512, 512LL * 4096, 256LL * 4096);
  gn_partials_kernel<<<65536, blk, 0, stream>>>(z64, sa, gnpart);
  gn_reduce_kernel<<<128, blk, 0, stream>>>(gnpart, gnst);
  gn_apply_fused_kernel<<<16384, blk, 0, stream>>>(z64, sa, gnst, gn_g, gn_b, out);
}